// Round 15
// baseline (303.536 us; speedup 1.0000x reference)
//
#include <hip/hip_runtime.h>

// GCN: 2x GraphConv(norm='both') + leaky_relu + linear classifier.
// Interface (validated R6/R7): x/W/b f32, src/dst int32, out f32.
// R15: agg+gemm fused per layer via LDS 128-node tiles (no aggbuf round
// trip, 6 launches). Build: packed bucket counting sort (R13/R14, no global
// atomics). ~57us/iter of harness tax (d_ws poison fill + d_in restore) is
// not ours. LDS stride 68 pads Phase-C b128 reads to conflict-free.

typedef __attribute__((ext_vector_type(8))) short short8;
typedef __attribute__((ext_vector_type(4))) float f32x4;

#define NPB 256      // partition blocks
#define BSH 9        // bucket shift (width 512)
#define BW  512      // bucket width; n <= 131072 -> <=256 buckets
#define TSH 7        // layer tile shift (128 nodes)
#define TW  128
#define STR 68       // LDS row stride (floats): 64 + 4 pad

__device__ __forceinline__ float b2f(unsigned short u) {
    return __uint_as_float(((unsigned int)u) << 16);
}
__device__ __forceinline__ unsigned short f2b(float f) {
    unsigned int i = __float_as_uint(f);
    unsigned int r = (i + 0x7FFFu + ((i >> 16) & 1u)) >> 16;  // RNE
    return (unsigned short)r;
}

// K1: per-partition-block LDS histograms by dst-bucket and src-bucket.
__global__ __launch_bounds__(256) void count_kernel(
    const int* __restrict__ src, const int* __restrict__ dst,
    int* __restrict__ cntD, int* __restrict__ cntS, int e, int chunk) {
    __shared__ int hD[256], hS[256];
    int t = threadIdx.x, pb = blockIdx.x;
    hD[t] = 0; hS[t] = 0;
    __syncthreads();
    int e0 = pb * chunk, e1 = min(e, e0 + chunk);
    for (int i = e0 + t; i < e1; i += 256) {
        atomicAdd(&hD[dst[i] >> BSH], 1);
        atomicAdd(&hS[src[i] >> BSH], 1);
    }
    __syncthreads();
    cntD[t * NPB + pb] = hD[t];
    cntS[t * NPB + pb] = hS[t];
}

// K2: exclusive scan of two 65536-int arrays (block 0: cntD, block 1: cntS)
__global__ __launch_bounds__(1024) void scanmat_kernel(int* __restrict__ cntD,
                                                       int* __restrict__ cntS) {
    int* a = (blockIdx.x == 0) ? cntD : cntS;
    __shared__ int s[1024];
    int t = threadIdx.x;
    int base = t * 64;
    int sum = 0;
    for (int j = 0; j < 64; j++) sum += a[base + j];
    s[t] = sum;
    __syncthreads();
    for (int d = 1; d < 1024; d <<= 1) {
        int x = (t >= d) ? s[t - d] : 0;
        __syncthreads();
        s[t] += x;
        __syncthreads();
    }
    int run = s[t] - sum;
    for (int j = 0; j < 64; j++) {
        int v = a[base + j];
        a[base + j] = run;
        run += v;
    }
}

// K3: partition. ebuf u32 = src<<9 | dstLocal; sbuf u16 = srcLocal.
__global__ __launch_bounds__(256) void part_kernel(
    const int* __restrict__ src, const int* __restrict__ dst,
    const int* __restrict__ cntD, const int* __restrict__ cntS,
    unsigned int* __restrict__ ebuf, unsigned short* __restrict__ sbuf,
    int e, int chunk) {
    __shared__ int cD[256], cS[256];
    int t = threadIdx.x, pb = blockIdx.x;
    cD[t] = cntD[t * NPB + pb];
    cS[t] = cntS[t * NPB + pb];
    __syncthreads();
    int e0 = pb * chunk, e1 = min(e, e0 + chunk);
    for (int i = e0 + t; i < e1; i += 256) {
        int s_ = src[i], d_ = dst[i];
        int pd = atomicAdd(&cD[d_ >> BSH], 1);
        ebuf[pd] = ((unsigned int)s_ << BSH) | (unsigned int)(d_ & (BW - 1));
        int ps_ = atomicAdd(&cS[s_ >> BSH], 1);
        sbuf[ps_] = (unsigned short)(s_ & (BW - 1));
    }
}

// K4: per-bucket fused: in-deg hist -> row/ii/cursors -> csr scatter;
// out-deg hist -> oi; x -> bf16*oi conversion for the bucket's nodes.
__global__ __launch_bounds__(256) void bucket_kernel(
    const unsigned int* __restrict__ ebuf, const unsigned short* __restrict__ sbuf,
    const int* __restrict__ cntD, const int* __restrict__ cntS,
    const float4* __restrict__ x4,
    int* __restrict__ row, float* __restrict__ ii, float* __restrict__ oi,
    int* __restrict__ csr, ushort4* __restrict__ xb, int n, int e) {
    __shared__ int cnt[BW], cur[BW], ocnt[BW], ps[256];
    __shared__ float ol[BW];
    int t = threadIdx.x, b = blockIdx.x;
    int v0 = b << BSH;
    int eb0 = cntD[b * NPB], eb1 = cntD[(b + 1) * NPB];
    int sb0 = cntS[b * NPB], sb1 = cntS[(b + 1) * NPB];
    cnt[t] = 0; cnt[t + 256] = 0;
    ocnt[t] = 0; ocnt[t + 256] = 0;
    __syncthreads();
    for (int i = eb0 + t; i < eb1; i += 256)
        atomicAdd(&cnt[ebuf[i] & (BW - 1)], 1);
    for (int i = sb0 + t; i < sb1; i += 256)
        atomicAdd(&ocnt[sbuf[i]], 1);
    __syncthreads();
    int c0 = cnt[2 * t], c1 = cnt[2 * t + 1];
    int pair = c0 + c1;
    ps[t] = pair;
    __syncthreads();
    for (int d = 1; d < 256; d <<= 1) {
        int x = (t >= d) ? ps[t - d] : 0;
        __syncthreads();
        ps[t] += x;
        __syncthreads();
    }
    int excl = ps[t] - pair;
    cur[2 * t] = excl;
    cur[2 * t + 1] = excl + c0;
    int v = v0 + 2 * t;
    if (v < n) {
        row[v] = eb0 + excl;
        ii[v] = rsqrtf((float)max(c0, 1));
    }
    if (v + 1 < n) {
        row[v + 1] = eb0 + excl + c0;
        ii[v + 1] = rsqrtf((float)max(c1, 1));
    }
    if (b == 0 && t == 0) row[n] = e;
    for (int j = t; j < BW; j += 256) {
        float o = rsqrtf((float)max(ocnt[j], 1));
        ol[j] = o;
        int vv = v0 + j;
        if (vv < n) oi[vv] = o;
    }
    __syncthreads();
    for (int i = eb0 + t; i < eb1; i += 256) {
        unsigned int p = ebuf[i];
        int r = atomicAdd(&cur[p & (BW - 1)], 1);
        csr[eb0 + r] = (int)(p >> BSH);
    }
    int nloc = min(BW, n - v0);
    for (int i = t; i < nloc * 16; i += 256) {
        int vl = i >> 4, q = i & 15;
        float s = ol[vl];
        float4 val = x4[(size_t)(v0 + vl) * 16 + q];
        xb[(size_t)(v0 + vl) * 16 + q] =
            make_ushort4(f2b(val.x * s), f2b(val.y * s), f2b(val.z * s), f2b(val.w * s));
    }
}

// Fused layer: one block per 128-node tile. Phase A: quad-gather aggregate
// into LDS (exclusive ownership, no atomics). Phase C: MFMA 16x16x32 bf16
// transform from LDS (A: m=lane&15, k=quad*8+j; C/D: col=lane&15,
// row=quad*4+reg -- verified R11). !FINAL: bf16 h1 pre-scaled by oi.
// FINAL: fused 64->2 classifier, f32 out.
template <bool FINAL>
__global__ __launch_bounds__(256) void layer_kernel(
    const ushort4* __restrict__ featb, const int* __restrict__ row,
    const int* __restrict__ csr, const float* __restrict__ ii,
    const float* __restrict__ oi,
    const float* __restrict__ W, const float* __restrict__ bias,
    const float* __restrict__ Wc, const float* __restrict__ bcl,
    void* __restrict__ out, int n) {
    __shared__ float accL[TW * STR];   // 34.8 KB
    int tid = threadIdx.x;
    int lane = tid & 63;
    int w = tid >> 6;                  // wave in block (0..3)
    int q = lane >> 4, s = lane & 15;
    int m15 = s, quad = q;
    int v0 = blockIdx.x << TSH;

    // hoist B fragments + bias (+classifier) into registers
    short8 bf[4][2];
#pragma unroll
    for (int nt = 0; nt < 4; nt++)
#pragma unroll
        for (int kk = 0; kk < 2; kk++)
#pragma unroll
            for (int j = 0; j < 8; j++)
                bf[nt][kk][j] = (short)f2b(W[(kk * 32 + quad * 8 + j) * 64 + nt * 16 + m15]);
    float bias_r[4];
#pragma unroll
    for (int nt = 0; nt < 4; nt++) bias_r[nt] = bias[nt * 16 + m15];
    float wc_r[4][2];
    float bc0 = 0.f, bc1 = 0.f;
    if constexpr (FINAL) {
#pragma unroll
        for (int nt = 0; nt < 4; nt++) {
            wc_r[nt][0] = Wc[(nt * 16 + m15) * 2];
            wc_r[nt][1] = Wc[(nt * 16 + m15) * 2 + 1];
        }
        bc0 = bcl[0];
        bc1 = bcl[1];
    }

    // ---- Phase A: aggregate tile nodes into LDS ----
    for (int gl = w; gl < TW / 4; gl += 4) {     // 8 groups per wave
        int vL = gl * 4 + q;
        int v = v0 + vL;
        bool valid = v < n;
        int base = 0, cnt = 0;
        if (valid) { base = row[v]; cnt = row[v + 1] - base; }
        float4 a = make_float4(0.f, 0.f, 0.f, 0.f);
        int j = 0;
        for (; j + 7 < cnt; j += 8) {
            int u[8];
#pragma unroll
            for (int k = 0; k < 8; k++) u[k] = csr[base + j + k];
#pragma unroll
            for (int k = 0; k < 8; k++) {
                ushort4 f = featb[(size_t)u[k] * 16 + s];
                a.x += b2f(f.x); a.y += b2f(f.y); a.z += b2f(f.z); a.w += b2f(f.w);
            }
        }
        for (; j + 3 < cnt; j += 4) {
            int u[4];
#pragma unroll
            for (int k = 0; k < 4; k++) u[k] = csr[base + j + k];
#pragma unroll
            for (int k = 0; k < 4; k++) {
                ushort4 f = featb[(size_t)u[k] * 16 + s];
                a.x += b2f(f.x); a.y += b2f(f.y); a.z += b2f(f.z); a.w += b2f(f.w);
            }
        }
        for (; j < cnt; j++) {
            ushort4 f = featb[(size_t)csr[base + j] * 16 + s];
            a.x += b2f(f.x); a.y += b2f(f.y); a.z += b2f(f.z); a.w += b2f(f.w);
        }
        *(float4*)&accL[vL * STR + s * 4] = a;   // exclusive slot, no atomic
    }
    __syncthreads();

    // ---- Phase C: MFMA transform from LDS ----
    for (int t8 = w; t8 < TW / 16; t8 += 4) {    // 2 tiles per wave
        int rl = t8 * 16;
        int rg = v0 + rl + m15;
        float iiv = ii[min(rg, n - 1)];

        short8 af[2];
#pragma unroll
        for (int kk = 0; kk < 2; kk++) {
            const float4* p = (const float4*)&accL[(rl + m15) * STR + kk * 32 + quad * 8];
            float4 x0 = p[0], x1 = p[1];
            af[kk][0] = (short)f2b(x0.x * iiv);
            af[kk][1] = (short)f2b(x0.y * iiv);
            af[kk][2] = (short)f2b(x0.z * iiv);
            af[kk][3] = (short)f2b(x0.w * iiv);
            af[kk][4] = (short)f2b(x1.x * iiv);
            af[kk][5] = (short)f2b(x1.y * iiv);
            af[kk][6] = (short)f2b(x1.z * iiv);
            af[kk][7] = (short)f2b(x1.w * iiv);
        }

        f32x4 acc[4];
#pragma unroll
        for (int nt = 0; nt < 4; nt++) {
            f32x4 z = {0.f, 0.f, 0.f, 0.f};
            z = __builtin_amdgcn_mfma_f32_16x16x32_bf16(af[0], bf[nt][0], z, 0, 0, 0);
            z = __builtin_amdgcn_mfma_f32_16x16x32_bf16(af[1], bf[nt][1], z, 0, 0, 0);
            acc[nt] = z;
        }

        if constexpr (!FINAL) {
#pragma unroll
            for (int r = 0; r < 4; r++) {
                int vr = v0 + rl + quad * 4 + r;
                float os = (vr < n) ? oi[vr] : 0.f;
#pragma unroll
                for (int nt = 0; nt < 4; nt++) {
                    float o = acc[nt][r] + bias_r[nt];
                    o = (o > 0.f) ? o : 0.01f * o;
                    if (vr < n)
                        ((unsigned short*)out)[(size_t)vr * 64 + nt * 16 + m15] = f2b(o * os);
                }
            }
        } else {
#pragma unroll
            for (int r = 0; r < 4; r++) {
                float p0 = 0.f, p1 = 0.f;
#pragma unroll
                for (int nt = 0; nt < 4; nt++) {
                    float o = acc[nt][r] + bias_r[nt];
                    o = (o > 0.f) ? o : 0.01f * o;
                    p0 = fmaf(o, wc_r[nt][0], p0);
                    p1 = fmaf(o, wc_r[nt][1], p1);
                }
#pragma unroll
                for (int off = 1; off < 16; off <<= 1) {
                    p0 += __shfl_xor(p0, off);
                    p1 += __shfl_xor(p1, off);
                }
                int vr = v0 + rl + quad * 4 + r;
                if (m15 == 0 && vr < n)
                    ((float2*)out)[vr] = make_float2(p0 + bc0, p1 + bc1);
            }
        }
    }
}

extern "C" void kernel_launch(void* const* d_in, const int* in_sizes, int n_in,
                              void* d_out, int out_size, void* d_ws, size_t ws_size,
                              hipStream_t stream) {
    const float* x  = (const float*)d_in[0];
    const int* src  = (const int*)d_in[1];
    const int* dst  = (const int*)d_in[2];
    const float* W1 = (const float*)d_in[3];
    const float* b1 = (const float*)d_in[4];
    const float* W2 = (const float*)d_in[5];
    const float* b2 = (const float*)d_in[6];
    const float* Wc = (const float*)d_in[7];
    const float* bc = (const float*)d_in[8];
    int n = in_sizes[0] / 64;
    int e = in_sizes[1];
    int total = n * 64;
    int nbuck = (n + BW - 1) >> BSH;
    int ntile = (n + TW - 1) >> TSH;

    char* ws = (char*)d_ws;
    size_t off = 0;
    auto take = [&](size_t bytes) -> char* {
        char* p = ws + off;
        off = (off + bytes + 255) & ~(size_t)255;
        return p;
    };
    int* cntD = (int*)take(256 * NPB * 4);
    int* cntS = (int*)take(256 * NPB * 4);
    unsigned int* ebuf = (unsigned int*)take((size_t)e * 4);     // 4 MB
    unsigned short* sbuf = (unsigned short*)take((size_t)e * 2); // 2 MB
    int* row  = (int*)take((size_t)(n + 1) * 4);
    int* csr  = (int*)take((size_t)e * 4);                       // 4 MB
    float* oi = (float*)take((size_t)n * 4);
    float* ii = (float*)take((size_t)n * 4);
    unsigned short* xb  = (unsigned short*)take((size_t)total * 2);  // 12.8 MB
    unsigned short* h1b = (unsigned short*)take((size_t)total * 2);  // 12.8 MB

    const int tb = 256;
    int chunk = (e + NPB - 1) / NPB;

    count_kernel<<<NPB, tb, 0, stream>>>(src, dst, cntD, cntS, e, chunk);
    scanmat_kernel<<<2, 1024, 0, stream>>>(cntD, cntS);
    part_kernel<<<NPB, tb, 0, stream>>>(src, dst, cntD, cntS, ebuf, sbuf, e, chunk);
    bucket_kernel<<<nbuck, tb, 0, stream>>>(ebuf, sbuf, cntD, cntS, (const float4*)x,
                                            row, ii, oi, csr, (ushort4*)xb, n, e);

    layer_kernel<false><<<ntile, tb, 0, stream>>>((const ushort4*)xb, row, csr, ii, oi,
                                                  W1, b1, nullptr, nullptr, h1b, n);
    layer_kernel<true><<<ntile, tb, 0, stream>>>((const ushort4*)h1b, row, csr, ii, oi,
                                                 W2, b2, Wc, bc, d_out, n);
}

// Round 16
// 243.716 us; speedup vs baseline: 1.2454x; 1.2454x over previous
//
#include <hip/hip_runtime.h>

// GCN: 2x GraphConv(norm='both') + leaky_relu + linear classifier.
// Interface (validated R6/R7): x/W/b f32, src/dst int32, out f32.
// R16 = R14 (best known) + degree-sorted node permutation for the agg
// kernels (bucket-local counting sort; wave's 4 quads get equal-degree
// nodes -> no gather-loop divergence). R8+R15 law: gather kernels must be
// lean (low VGPR, no LDS) -- never fuse them with the GEMM.
// ~57us/iter harness tax (d_ws poison + d_in restore) is not ours.

typedef __attribute__((ext_vector_type(8))) short short8;
typedef __attribute__((ext_vector_type(4))) float f32x4;

#define NPB 256      // partition blocks
#define BSH 9        // bucket shift (width 512)
#define BW  512      // bucket width; n <= 131072 -> <=256 buckets

__device__ __forceinline__ float b2f(unsigned short u) {
    return __uint_as_float(((unsigned int)u) << 16);
}
__device__ __forceinline__ unsigned short f2b(float f) {
    unsigned int i = __float_as_uint(f);
    unsigned int r = (i + 0x7FFFu + ((i >> 16) & 1u)) >> 16;  // RNE
    return (unsigned short)r;
}

// K1: per-partition-block LDS histograms by dst-bucket and src-bucket.
__global__ __launch_bounds__(256) void count_kernel(
    const int* __restrict__ src, const int* __restrict__ dst,
    int* __restrict__ cntD, int* __restrict__ cntS, int e, int chunk) {
    __shared__ int hD[256], hS[256];
    int t = threadIdx.x, pb = blockIdx.x;
    hD[t] = 0; hS[t] = 0;
    __syncthreads();
    int e0 = pb * chunk, e1 = min(e, e0 + chunk);
    for (int i = e0 + t; i < e1; i += 256) {
        atomicAdd(&hD[dst[i] >> BSH], 1);
        atomicAdd(&hS[src[i] >> BSH], 1);
    }
    __syncthreads();
    cntD[t * NPB + pb] = hD[t];
    cntS[t * NPB + pb] = hS[t];
}

// K2: exclusive scan of two 65536-int arrays (block 0: cntD, block 1: cntS)
__global__ __launch_bounds__(1024) void scanmat_kernel(int* __restrict__ cntD,
                                                       int* __restrict__ cntS) {
    int* a = (blockIdx.x == 0) ? cntD : cntS;
    __shared__ int s[1024];
    int t = threadIdx.x;
    int base = t * 64;
    int sum = 0;
    for (int j = 0; j < 64; j++) sum += a[base + j];
    s[t] = sum;
    __syncthreads();
    for (int d = 1; d < 1024; d <<= 1) {
        int x = (t >= d) ? s[t - d] : 0;
        __syncthreads();
        s[t] += x;
        __syncthreads();
    }
    int run = s[t] - sum;
    for (int j = 0; j < 64; j++) {
        int v = a[base + j];
        a[base + j] = run;
        run += v;
    }
}

// K3: partition. ebuf u32 = src<<9 | dstLocal; sbuf u16 = srcLocal.
__global__ __launch_bounds__(256) void part_kernel(
    const int* __restrict__ src, const int* __restrict__ dst,
    const int* __restrict__ cntD, const int* __restrict__ cntS,
    unsigned int* __restrict__ ebuf, unsigned short* __restrict__ sbuf,
    int e, int chunk) {
    __shared__ int cD[256], cS[256];
    int t = threadIdx.x, pb = blockIdx.x;
    cD[t] = cntD[t * NPB + pb];
    cS[t] = cntS[t * NPB + pb];
    __syncthreads();
    int e0 = pb * chunk, e1 = min(e, e0 + chunk);
    for (int i = e0 + t; i < e1; i += 256) {
        int s_ = src[i], d_ = dst[i];
        int pd = atomicAdd(&cD[d_ >> BSH], 1);
        ebuf[pd] = ((unsigned int)s_ << BSH) | (unsigned int)(d_ & (BW - 1));
        int ps_ = atomicAdd(&cS[s_ >> BSH], 1);
        sbuf[ps_] = (unsigned short)(s_ & (BW - 1));
    }
}

// K4: per-bucket fused: in-deg hist -> row/ii/cursors -> csr scatter;
// out-deg hist -> oi; x -> bf16*oi; degree-sorted local perm.
__global__ __launch_bounds__(256) void bucket_kernel(
    const unsigned int* __restrict__ ebuf, const unsigned short* __restrict__ sbuf,
    const int* __restrict__ cntD, const int* __restrict__ cntS,
    const float4* __restrict__ x4,
    int* __restrict__ row, float* __restrict__ ii, float* __restrict__ oi,
    int* __restrict__ csr, ushort4* __restrict__ xb, int* __restrict__ perm,
    int n, int e) {
    __shared__ int cnt[BW], cur[BW], ocnt[BW], ps[256];
    __shared__ float ol[BW];
    __shared__ int dh[64];
    int t = threadIdx.x, b = blockIdx.x;
    int v0 = b << BSH;
    int eb0 = cntD[b * NPB], eb1 = cntD[(b + 1) * NPB];
    int sb0 = cntS[b * NPB], sb1 = cntS[(b + 1) * NPB];
    int nloc = min(BW, n - v0);
    cnt[t] = 0; cnt[t + 256] = 0;
    ocnt[t] = 0; ocnt[t + 256] = 0;
    if (t < 64) dh[t] = 0;
    __syncthreads();
    for (int i = eb0 + t; i < eb1; i += 256)
        atomicAdd(&cnt[ebuf[i] & (BW - 1)], 1);
    for (int i = sb0 + t; i < sb1; i += 256)
        atomicAdd(&ocnt[sbuf[i]], 1);
    __syncthreads();
    // scan in-degrees (2 per thread) -> row offsets + cursors + ii
    int c0 = cnt[2 * t], c1 = cnt[2 * t + 1];
    int pair = c0 + c1;
    ps[t] = pair;
    __syncthreads();
    for (int d = 1; d < 256; d <<= 1) {
        int x = (t >= d) ? ps[t - d] : 0;
        __syncthreads();
        ps[t] += x;
        __syncthreads();
    }
    int excl = ps[t] - pair;
    cur[2 * t] = excl;
    cur[2 * t + 1] = excl + c0;
    int v = v0 + 2 * t;
    if (v < n) {
        row[v] = eb0 + excl;
        ii[v] = rsqrtf((float)max(c0, 1));
    }
    if (v + 1 < n) {
        row[v + 1] = eb0 + excl + c0;
        ii[v + 1] = rsqrtf((float)max(c1, 1));
    }
    if (b == 0 && t == 0) row[n] = e;
    // out-degree rsqrt -> LDS + global
    for (int j = t; j < BW; j += 256) {
        float o = rsqrtf((float)max(ocnt[j], 1));
        ol[j] = o;
        int vv = v0 + j;
        if (vv < n) oi[vv] = o;
    }
    // degree histogram of valid local nodes (clamp 63)
    for (int j = t; j < nloc; j += 256)
        atomicAdd(&dh[min(cnt[j], 63)], 1);
    __syncthreads();
    if (t == 0) {  // tiny serial exclusive scan of 64 bins
        int acc = 0;
        for (int d = 0; d < 64; d++) { int x = dh[d]; dh[d] = acc; acc += x; }
    }
    __syncthreads();
    // degree-sorted permutation: consecutive perm entries have equal degree
    for (int j = t; j < nloc; j += 256) {
        int pos = atomicAdd(&dh[min(cnt[j], 63)], 1);
        perm[v0 + pos] = v0 + j;
    }
    // csr scatter (L2-local)
    for (int i = eb0 + t; i < eb1; i += 256) {
        unsigned int p = ebuf[i];
        int r = atomicAdd(&cur[p & (BW - 1)], 1);
        csr[eb0 + r] = (int)(p >> BSH);
    }
    // x -> bf16 * oi (coalesced)
    for (int i = t; i < nloc * 16; i += 256) {
        int vl = i >> 4, q = i & 15;
        float s = ol[vl];
        float4 val = x4[(size_t)(v0 + vl) * 16 + q];
        xb[(size_t)(v0 + vl) * 16 + q] =
            make_ushort4(f2b(val.x * s), f2b(val.y * s), f2b(val.z * s), f2b(val.w * s));
    }
}

// Aggregate: wave = 4 nodes (degree-matched via perm); quad q owns one node;
// sublane s = lane&15 owns feats 4s..4s+3 (ushort4). Unroll 8.
__global__ __launch_bounds__(256) void agg_kernel(
    const ushort4* __restrict__ featb, const int* __restrict__ row,
    const int* __restrict__ csr, const int* __restrict__ perm,
    float4* __restrict__ out4, int n, int nwaves) {
    int lane = threadIdx.x & 63;
    int q = lane >> 4, s = lane & 15;
    int wid = blockIdx.x * (blockDim.x >> 6) + (threadIdx.x >> 6);
    int ngroups = (n + 3) >> 2;

    for (int g = wid; g < ngroups; g += nwaves) {
        int v = (g << 2) + q;
        bool valid = v < n;
        int pv = 0, base = 0, cnt = 0;
        if (valid) {
            pv = perm[v];
            base = row[pv];
            cnt = row[pv + 1] - base;
        }
        float4 a = make_float4(0.f, 0.f, 0.f, 0.f);
        int j = 0;
        for (; j + 7 < cnt; j += 8) {
            int u[8];
#pragma unroll
            for (int k = 0; k < 8; k++) u[k] = csr[base + j + k];
#pragma unroll
            for (int k = 0; k < 8; k++) {
                ushort4 f = featb[(size_t)u[k] * 16 + s];
                a.x += b2f(f.x); a.y += b2f(f.y); a.z += b2f(f.z); a.w += b2f(f.w);
            }
        }
        for (; j + 3 < cnt; j += 4) {
            int u[4];
#pragma unroll
            for (int k = 0; k < 4; k++) u[k] = csr[base + j + k];
#pragma unroll
            for (int k = 0; k < 4; k++) {
                ushort4 f = featb[(size_t)u[k] * 16 + s];
                a.x += b2f(f.x); a.y += b2f(f.y); a.z += b2f(f.z); a.w += b2f(f.w);
            }
        }
        for (; j < cnt; j++) {
            ushort4 f = featb[(size_t)csr[base + j] * 16 + s];
            a.x += b2f(f.x); a.y += b2f(f.y); a.z += b2f(f.z); a.w += b2f(f.w);
        }
        if (valid) out4[(size_t)pv * 16 + s] = a;
    }
}

// Transform: [n x 64] @ W[64 x 64] via mfma_f32_16x16x32_bf16 (layout
// verified R11). ii folded into A; bias+leaky epilogue. !FINAL: bf16 h1
// pre-scaled by oi. FINAL: fused 64->2 classifier, f32 out.
template <bool FINAL>
__global__ __launch_bounds__(256) void gemm_kernel(
    const float* __restrict__ agg, const float* __restrict__ ii,
    const float* __restrict__ oi,
    const float* __restrict__ W, const float* __restrict__ bias,
    const float* __restrict__ Wc, const float* __restrict__ bcl,
    void* __restrict__ out, int n, int nwaves) {
    int lane = threadIdx.x & 63;
    int m15 = lane & 15, quad = lane >> 4;
    int wid = blockIdx.x * (blockDim.x >> 6) + (threadIdx.x >> 6);
    int ngroups = (n + 15) >> 4;

    short8 bf[4][2];
#pragma unroll
    for (int nt = 0; nt < 4; nt++)
#pragma unroll
        for (int kk = 0; kk < 2; kk++)
#pragma unroll
            for (int j = 0; j < 8; j++)
                bf[nt][kk][j] = (short)f2b(W[(kk * 32 + quad * 8 + j) * 64 + nt * 16 + m15]);

    float bias_r[4];
#pragma unroll
    for (int nt = 0; nt < 4; nt++) bias_r[nt] = bias[nt * 16 + m15];

    float wc_r[4][2];
    float bc0 = 0.f, bc1 = 0.f;
    if constexpr (FINAL) {
#pragma unroll
        for (int nt = 0; nt < 4; nt++) {
            wc_r[nt][0] = Wc[(nt * 16 + m15) * 2];
            wc_r[nt][1] = Wc[(nt * 16 + m15) * 2 + 1];
        }
        bc0 = bcl[0];
        bc1 = bcl[1];
    }

    for (int g = wid; g < ngroups; g += nwaves) {
        int rbase = g << 4;
        int rm = min(rbase + m15, n - 1);
        float iiv = ii[rm];

        short8 af[2];
#pragma unroll
        for (int kk = 0; kk < 2; kk++) {
            const float4* p = (const float4*)(agg + (size_t)rm * 64 + kk * 32 + quad * 8);
            float4 x0 = p[0], x1 = p[1];
            af[kk][0] = (short)f2b(x0.x * iiv);
            af[kk][1] = (short)f2b(x0.y * iiv);
            af[kk][2] = (short)f2b(x0.z * iiv);
            af[kk][3] = (short)f2b(x0.w * iiv);
            af[kk][4] = (short)f2b(x1.x * iiv);
            af[kk][5] = (short)f2b(x1.y * iiv);
            af[kk][6] = (short)f2b(x1.z * iiv);
            af[kk][7] = (short)f2b(x1.w * iiv);
        }

        f32x4 acc[4];
#pragma unroll
        for (int nt = 0; nt < 4; nt++) {
            f32x4 z = {0.f, 0.f, 0.f, 0.f};
            z = __builtin_amdgcn_mfma_f32_16x16x32_bf16(af[0], bf[nt][0], z, 0, 0, 0);
            z = __builtin_amdgcn_mfma_f32_16x16x32_bf16(af[1], bf[nt][1], z, 0, 0, 0);
            acc[nt] = z;
        }

        if constexpr (!FINAL) {
#pragma unroll
            for (int r = 0; r < 4; r++) {
                int vr = rbase + quad * 4 + r;
                float os = (vr < n) ? oi[vr] : 0.f;
#pragma unroll
                for (int nt = 0; nt < 4; nt++) {
                    float o = acc[nt][r] + bias_r[nt];
                    o = (o > 0.f) ? o : 0.01f * o;
                    if (vr < n)
                        ((unsigned short*)out)[(size_t)vr * 64 + nt * 16 + m15] = f2b(o * os);
                }
            }
        } else {
#pragma unroll
            for (int r = 0; r < 4; r++) {
                float p0 = 0.f, p1 = 0.f;
#pragma unroll
                for (int nt = 0; nt < 4; nt++) {
                    float o = acc[nt][r] + bias_r[nt];
                    o = (o > 0.f) ? o : 0.01f * o;
                    p0 = fmaf(o, wc_r[nt][0], p0);
                    p1 = fmaf(o, wc_r[nt][1], p1);
                }
#pragma unroll
                for (int off = 1; off < 16; off <<= 1) {
                    p0 += __shfl_xor(p0, off);
                    p1 += __shfl_xor(p1, off);
                }
                int vr = rbase + quad * 4 + r;
                if (m15 == 0 && vr < n)
                    ((float2*)out)[vr] = make_float2(p0 + bc0, p1 + bc1);
            }
        }
    }
}

extern "C" void kernel_launch(void* const* d_in, const int* in_sizes, int n_in,
                              void* d_out, int out_size, void* d_ws, size_t ws_size,
                              hipStream_t stream) {
    const float* x  = (const float*)d_in[0];
    const int* src  = (const int*)d_in[1];
    const int* dst  = (const int*)d_in[2];
    const float* W1 = (const float*)d_in[3];
    const float* b1 = (const float*)d_in[4];
    const float* W2 = (const float*)d_in[5];
    const float* b2 = (const float*)d_in[6];
    const float* Wc = (const float*)d_in[7];
    const float* bc = (const float*)d_in[8];
    int n = in_sizes[0] / 64;
    int e = in_sizes[1];
    int total = n * 64;
    int nbuck = (n + BW - 1) >> BSH;

    char* ws = (char*)d_ws;
    size_t off = 0;
    auto take = [&](size_t bytes) -> char* {
        char* p = ws + off;
        off = (off + bytes + 255) & ~(size_t)255;
        return p;
    };
    int* cntD = (int*)take(256 * NPB * 4);
    int* cntS = (int*)take(256 * NPB * 4);
    unsigned int* ebuf = (unsigned int*)take((size_t)e * 4);     // 4 MB
    unsigned short* sbuf = (unsigned short*)take((size_t)e * 2); // 2 MB
    int* row  = (int*)take((size_t)(n + 1) * 4);
    int* csr  = (int*)take((size_t)e * 4);                       // 4 MB
    int* perm = (int*)take((size_t)n * 4);
    float* oi = (float*)take((size_t)n * 4);
    float* ii = (float*)take((size_t)n * 4);
    unsigned short* xb  = (unsigned short*)take((size_t)total * 2);  // 12.8 MB
    unsigned short* h1b = (unsigned short*)take((size_t)total * 2);  // 12.8 MB
    float* aggbuf = (float*)take((size_t)total * 4);             // 25.6 MB

    const int tb = 256;
    int chunk = (e + NPB - 1) / NPB;

    count_kernel<<<NPB, tb, 0, stream>>>(src, dst, cntD, cntS, e, chunk);
    scanmat_kernel<<<2, 1024, 0, stream>>>(cntD, cntS);
    part_kernel<<<NPB, tb, 0, stream>>>(src, dst, cntD, cntS, ebuf, sbuf, e, chunk);
    bucket_kernel<<<nbuck, tb, 0, stream>>>(ebuf, sbuf, cntD, cntS, (const float4*)x,
                                            row, ii, oi, csr, (ushort4*)xb, perm, n, e);

    const int ablocks = 2048;
    const int awaves = ablocks * (tb / 64);
    const int gblocks = 512;
    const int gwaves = gblocks * (tb / 64);

    // layer 1
    agg_kernel<<<ablocks, tb, 0, stream>>>((const ushort4*)xb, row, csr, perm,
                                           (float4*)aggbuf, n, awaves);
    gemm_kernel<false><<<gblocks, tb, 0, stream>>>(aggbuf, ii, oi, W1, b1,
                                                   nullptr, nullptr, h1b, n, gwaves);
    // layer 2
    agg_kernel<<<ablocks, tb, 0, stream>>>((const ushort4*)h1b, row, csr, perm,
                                           (float4*)aggbuf, n, awaves);
    gemm_kernel<true><<<gblocks, tb, 0, stream>>>(aggbuf, ii, nullptr, W2, b2,
                                                  Wc, bc, d_out, n, gwaves);
}

// Round 17
// 230.189 us; speedup vs baseline: 1.3186x; 1.0588x over previous
//
#include <hip/hip_runtime.h>

// GCN: 2x GraphConv(norm='both') + leaky_relu + linear classifier.
// Interface (validated R6/R7): x/W/b f32, src/dst int32, out f32.
// R17 = exact revert to R14 (best known: 234.7us). R15 (agg+gemm fusion:
// occupancy collapse, 303us) and R16 (degree-sort perm: scattered writes,
// 243us) both regressed -- the agg kernel is latency-bound and must stay
// lean + coalesced. Build: packed bucket counting sort, no global atomics.
// ~57us/iter harness tax (268MB d_ws poison fill + d_in restore) is not ours.

typedef __attribute__((ext_vector_type(8))) short short8;
typedef __attribute__((ext_vector_type(4))) float f32x4;

#define NPB 256      // partition blocks
#define BSH 9        // bucket shift (width 512)
#define BW  512      // bucket width; n <= 131072 -> <=256 buckets

__device__ __forceinline__ float b2f(unsigned short u) {
    return __uint_as_float(((unsigned int)u) << 16);
}
__device__ __forceinline__ unsigned short f2b(float f) {
    unsigned int i = __float_as_uint(f);
    unsigned int r = (i + 0x7FFFu + ((i >> 16) & 1u)) >> 16;  // RNE
    return (unsigned short)r;
}

// K1: per-partition-block LDS histograms by dst-bucket and src-bucket.
__global__ __launch_bounds__(256) void count_kernel(
    const int* __restrict__ src, const int* __restrict__ dst,
    int* __restrict__ cntD, int* __restrict__ cntS, int e, int chunk) {
    __shared__ int hD[256], hS[256];
    int t = threadIdx.x, pb = blockIdx.x;
    hD[t] = 0; hS[t] = 0;
    __syncthreads();
    int e0 = pb * chunk, e1 = min(e, e0 + chunk);
    for (int i = e0 + t; i < e1; i += 256) {
        atomicAdd(&hD[dst[i] >> BSH], 1);
        atomicAdd(&hS[src[i] >> BSH], 1);
    }
    __syncthreads();
    cntD[t * NPB + pb] = hD[t];
    cntS[t * NPB + pb] = hS[t];
}

// K2: exclusive scan of two 65536-int arrays (block 0: cntD, block 1: cntS)
__global__ __launch_bounds__(1024) void scanmat_kernel(int* __restrict__ cntD,
                                                       int* __restrict__ cntS) {
    int* a = (blockIdx.x == 0) ? cntD : cntS;
    __shared__ int s[1024];
    int t = threadIdx.x;
    int base = t * 64;
    int sum = 0;
    for (int j = 0; j < 64; j++) sum += a[base + j];
    s[t] = sum;
    __syncthreads();
    for (int d = 1; d < 1024; d <<= 1) {
        int x = (t >= d) ? s[t - d] : 0;
        __syncthreads();
        s[t] += x;
        __syncthreads();
    }
    int run = s[t] - sum;
    for (int j = 0; j < 64; j++) {
        int v = a[base + j];
        a[base + j] = run;
        run += v;
    }
}

// K3: partition. ebuf u32 = src<<9 | dstLocal; sbuf u16 = srcLocal.
__global__ __launch_bounds__(256) void part_kernel(
    const int* __restrict__ src, const int* __restrict__ dst,
    const int* __restrict__ cntD, const int* __restrict__ cntS,
    unsigned int* __restrict__ ebuf, unsigned short* __restrict__ sbuf,
    int e, int chunk) {
    __shared__ int cD[256], cS[256];
    int t = threadIdx.x, pb = blockIdx.x;
    cD[t] = cntD[t * NPB + pb];
    cS[t] = cntS[t * NPB + pb];
    __syncthreads();
    int e0 = pb * chunk, e1 = min(e, e0 + chunk);
    for (int i = e0 + t; i < e1; i += 256) {
        int s_ = src[i], d_ = dst[i];
        int pd = atomicAdd(&cD[d_ >> BSH], 1);
        ebuf[pd] = ((unsigned int)s_ << BSH) | (unsigned int)(d_ & (BW - 1));
        int ps_ = atomicAdd(&cS[s_ >> BSH], 1);
        sbuf[ps_] = (unsigned short)(s_ & (BW - 1));
    }
}

// K4: per-bucket fused: in-deg hist -> row/ii/cursors -> csr scatter;
// out-deg hist -> oi; x -> bf16*oi conversion for the bucket's nodes.
__global__ __launch_bounds__(256) void bucket_kernel(
    const unsigned int* __restrict__ ebuf, const unsigned short* __restrict__ sbuf,
    const int* __restrict__ cntD, const int* __restrict__ cntS,
    const float4* __restrict__ x4,
    int* __restrict__ row, float* __restrict__ ii, float* __restrict__ oi,
    int* __restrict__ csr, ushort4* __restrict__ xb, int n, int e) {
    __shared__ int cnt[BW], cur[BW], ocnt[BW], ps[256];
    __shared__ float ol[BW];
    int t = threadIdx.x, b = blockIdx.x;
    int v0 = b << BSH;
    int eb0 = cntD[b * NPB], eb1 = cntD[(b + 1) * NPB];
    int sb0 = cntS[b * NPB], sb1 = cntS[(b + 1) * NPB];
    cnt[t] = 0; cnt[t + 256] = 0;
    ocnt[t] = 0; ocnt[t + 256] = 0;
    __syncthreads();
    for (int i = eb0 + t; i < eb1; i += 256)
        atomicAdd(&cnt[ebuf[i] & (BW - 1)], 1);
    for (int i = sb0 + t; i < sb1; i += 256)
        atomicAdd(&ocnt[sbuf[i]], 1);
    __syncthreads();
    int c0 = cnt[2 * t], c1 = cnt[2 * t + 1];
    int pair = c0 + c1;
    ps[t] = pair;
    __syncthreads();
    for (int d = 1; d < 256; d <<= 1) {
        int x = (t >= d) ? ps[t - d] : 0;
        __syncthreads();
        ps[t] += x;
        __syncthreads();
    }
    int excl = ps[t] - pair;
    cur[2 * t] = excl;
    cur[2 * t + 1] = excl + c0;
    int v = v0 + 2 * t;
    if (v < n) {
        row[v] = eb0 + excl;
        ii[v] = rsqrtf((float)max(c0, 1));
    }
    if (v + 1 < n) {
        row[v + 1] = eb0 + excl + c0;
        ii[v + 1] = rsqrtf((float)max(c1, 1));
    }
    if (b == 0 && t == 0) row[n] = e;
    for (int j = t; j < BW; j += 256) {
        float o = rsqrtf((float)max(ocnt[j], 1));
        ol[j] = o;
        int vv = v0 + j;
        if (vv < n) oi[vv] = o;
    }
    __syncthreads();
    for (int i = eb0 + t; i < eb1; i += 256) {
        unsigned int p = ebuf[i];
        int r = atomicAdd(&cur[p & (BW - 1)], 1);
        csr[eb0 + r] = (int)(p >> BSH);
    }
    int nloc = min(BW, n - v0);
    for (int i = t; i < nloc * 16; i += 256) {
        int vl = i >> 4, q = i & 15;
        float s = ol[vl];
        float4 val = x4[(size_t)(v0 + vl) * 16 + q];
        xb[(size_t)(v0 + vl) * 16 + q] =
            make_ushort4(f2b(val.x * s), f2b(val.y * s), f2b(val.z * s), f2b(val.w * s));
    }
}

// Aggregate: wave = 4 nodes; quad q owns node vbase+q; sublane s = lane&15
// owns feats 4s..4s+3 (ushort4 = 8B). Features pre-scaled by oi. Unroll 8.
__global__ __launch_bounds__(256) void agg_kernel(
    const ushort4* __restrict__ featb, const int* __restrict__ row,
    const int* __restrict__ csr, float4* __restrict__ out4,
    int n, int nwaves) {
    int lane = threadIdx.x & 63;
    int q = lane >> 4, s = lane & 15;
    int wid = blockIdx.x * (blockDim.x >> 6) + (threadIdx.x >> 6);
    int ngroups = (n + 3) >> 2;

    for (int g = wid; g < ngroups; g += nwaves) {
        int v = (g << 2) + q;
        bool valid = v < n;
        int base = 0, cnt = 0;
        if (valid) { base = row[v]; cnt = row[v + 1] - base; }
        float4 a = make_float4(0.f, 0.f, 0.f, 0.f);
        int j = 0;
        for (; j + 7 < cnt; j += 8) {
            int u[8];
#pragma unroll
            for (int k = 0; k < 8; k++) u[k] = csr[base + j + k];
#pragma unroll
            for (int k = 0; k < 8; k++) {
                ushort4 f = featb[(size_t)u[k] * 16 + s];
                a.x += b2f(f.x); a.y += b2f(f.y); a.z += b2f(f.z); a.w += b2f(f.w);
            }
        }
        for (; j + 3 < cnt; j += 4) {
            int u[4];
#pragma unroll
            for (int k = 0; k < 4; k++) u[k] = csr[base + j + k];
#pragma unroll
            for (int k = 0; k < 4; k++) {
                ushort4 f = featb[(size_t)u[k] * 16 + s];
                a.x += b2f(f.x); a.y += b2f(f.y); a.z += b2f(f.z); a.w += b2f(f.w);
            }
        }
        for (; j < cnt; j++) {
            ushort4 f = featb[(size_t)csr[base + j] * 16 + s];
            a.x += b2f(f.x); a.y += b2f(f.y); a.z += b2f(f.z); a.w += b2f(f.w);
        }
        if (valid) out4[(size_t)v * 16 + s] = a;
    }
}

// Transform: [n x 64] @ W[64 x 64] via mfma_f32_16x16x32_bf16 (layout
// verified R11). ii folded into A; bias+leaky epilogue. !FINAL: bf16 h1
// pre-scaled by oi. FINAL: fused 64->2 classifier, f32 out.
template <bool FINAL>
__global__ __launch_bounds__(256) void gemm_kernel(
    const float* __restrict__ agg, const float* __restrict__ ii,
    const float* __restrict__ oi,
    const float* __restrict__ W, const float* __restrict__ bias,
    const float* __restrict__ Wc, const float* __restrict__ bcl,
    void* __restrict__ out, int n, int nwaves) {
    int lane = threadIdx.x & 63;
    int m15 = lane & 15, quad = lane >> 4;
    int wid = blockIdx.x * (blockDim.x >> 6) + (threadIdx.x >> 6);
    int ngroups = (n + 15) >> 4;

    short8 bf[4][2];
#pragma unroll
    for (int nt = 0; nt < 4; nt++)
#pragma unroll
        for (int kk = 0; kk < 2; kk++)
#pragma unroll
            for (int j = 0; j < 8; j++)
                bf[nt][kk][j] = (short)f2b(W[(kk * 32 + quad * 8 + j) * 64 + nt * 16 + m15]);

    float bias_r[4];
#pragma unroll
    for (int nt = 0; nt < 4; nt++) bias_r[nt] = bias[nt * 16 + m15];

    float wc_r[4][2];
    float bc0 = 0.f, bc1 = 0.f;
    if constexpr (FINAL) {
#pragma unroll
        for (int nt = 0; nt < 4; nt++) {
            wc_r[nt][0] = Wc[(nt * 16 + m15) * 2];
            wc_r[nt][1] = Wc[(nt * 16 + m15) * 2 + 1];
        }
        bc0 = bcl[0];
        bc1 = bcl[1];
    }

    for (int g = wid; g < ngroups; g += nwaves) {
        int rbase = g << 4;
        int rm = min(rbase + m15, n - 1);
        float iiv = ii[rm];

        short8 af[2];
#pragma unroll
        for (int kk = 0; kk < 2; kk++) {
            const float4* p = (const float4*)(agg + (size_t)rm * 64 + kk * 32 + quad * 8);
            float4 x0 = p[0], x1 = p[1];
            af[kk][0] = (short)f2b(x0.x * iiv);
            af[kk][1] = (short)f2b(x0.y * iiv);
            af[kk][2] = (short)f2b(x0.z * iiv);
            af[kk][3] = (short)f2b(x0.w * iiv);
            af[kk][4] = (short)f2b(x1.x * iiv);
            af[kk][5] = (short)f2b(x1.y * iiv);
            af[kk][6] = (short)f2b(x1.z * iiv);
            af[kk][7] = (short)f2b(x1.w * iiv);
        }

        f32x4 acc[4];
#pragma unroll
        for (int nt = 0; nt < 4; nt++) {
            f32x4 z = {0.f, 0.f, 0.f, 0.f};
            z = __builtin_amdgcn_mfma_f32_16x16x32_bf16(af[0], bf[nt][0], z, 0, 0, 0);
            z = __builtin_amdgcn_mfma_f32_16x16x32_bf16(af[1], bf[nt][1], z, 0, 0, 0);
            acc[nt] = z;
        }

        if constexpr (!FINAL) {
#pragma unroll
            for (int r = 0; r < 4; r++) {
                int vr = rbase + quad * 4 + r;
                float os = (vr < n) ? oi[vr] : 0.f;
#pragma unroll
                for (int nt = 0; nt < 4; nt++) {
                    float o = acc[nt][r] + bias_r[nt];
                    o = (o > 0.f) ? o : 0.01f * o;
                    if (vr < n)
                        ((unsigned short*)out)[(size_t)vr * 64 + nt * 16 + m15] = f2b(o * os);
                }
            }
        } else {
#pragma unroll
            for (int r = 0; r < 4; r++) {
                float p0 = 0.f, p1 = 0.f;
#pragma unroll
                for (int nt = 0; nt < 4; nt++) {
                    float o = acc[nt][r] + bias_r[nt];
                    o = (o > 0.f) ? o : 0.01f * o;
                    p0 = fmaf(o, wc_r[nt][0], p0);
                    p1 = fmaf(o, wc_r[nt][1], p1);
                }
#pragma unroll
                for (int off = 1; off < 16; off <<= 1) {
                    p0 += __shfl_xor(p0, off);
                    p1 += __shfl_xor(p1, off);
                }
                int vr = rbase + quad * 4 + r;
                if (m15 == 0 && vr < n)
                    ((float2*)out)[vr] = make_float2(p0 + bc0, p1 + bc1);
            }
        }
    }
}

extern "C" void kernel_launch(void* const* d_in, const int* in_sizes, int n_in,
                              void* d_out, int out_size, void* d_ws, size_t ws_size,
                              hipStream_t stream) {
    const float* x  = (const float*)d_in[0];
    const int* src  = (const int*)d_in[1];
    const int* dst  = (const int*)d_in[2];
    const float* W1 = (const float*)d_in[3];
    const float* b1 = (const float*)d_in[4];
    const float* W2 = (const float*)d_in[5];
    const float* b2 = (const float*)d_in[6];
    const float* Wc = (const float*)d_in[7];
    const float* bc = (const float*)d_in[8];
    int n = in_sizes[0] / 64;
    int e = in_sizes[1];
    int total = n * 64;
    int nbuck = (n + BW - 1) >> BSH;

    char* ws = (char*)d_ws;
    size_t off = 0;
    auto take = [&](size_t bytes) -> char* {
        char* p = ws + off;
        off = (off + bytes + 255) & ~(size_t)255;
        return p;
    };
    int* cntD = (int*)take(256 * NPB * 4);
    int* cntS = (int*)take(256 * NPB * 4);
    unsigned int* ebuf = (unsigned int*)take((size_t)e * 4);     // 4 MB
    unsigned short* sbuf = (unsigned short*)take((size_t)e * 2); // 2 MB
    int* row  = (int*)take((size_t)(n + 1) * 4);
    int* csr  = (int*)take((size_t)e * 4);                       // 4 MB
    float* oi = (float*)take((size_t)n * 4);
    float* ii = (float*)take((size_t)n * 4);
    unsigned short* xb  = (unsigned short*)take((size_t)total * 2);  // 12.8 MB
    unsigned short* h1b = (unsigned short*)take((size_t)total * 2);  // 12.8 MB
    float* aggbuf = (float*)take((size_t)total * 4);             // 25.6 MB

    const int tb = 256;
    int chunk = (e + NPB - 1) / NPB;

    count_kernel<<<NPB, tb, 0, stream>>>(src, dst, cntD, cntS, e, chunk);
    scanmat_kernel<<<2, 1024, 0, stream>>>(cntD, cntS);
    part_kernel<<<NPB, tb, 0, stream>>>(src, dst, cntD, cntS, ebuf, sbuf, e, chunk);
    bucket_kernel<<<nbuck, tb, 0, stream>>>(ebuf, sbuf, cntD, cntS, (const float4*)x,
                                            row, ii, oi, csr, (ushort4*)xb, n, e);

    const int ablocks = 2048;
    const int awaves = ablocks * (tb / 64);
    const int gblocks = 512;
    const int gwaves = gblocks * (tb / 64);

    // layer 1
    agg_kernel<<<ablocks, tb, 0, stream>>>((const ushort4*)xb, row, csr,
                                           (float4*)aggbuf, n, awaves);
    gemm_kernel<false><<<gblocks, tb, 0, stream>>>(aggbuf, ii, oi, W1, b1,
                                                   nullptr, nullptr, h1b, n, gwaves);
    // layer 2
    agg_kernel<<<ablocks, tb, 0, stream>>>((const ushort4*)h1b, row, csr,
                                           (float4*)aggbuf, n, awaves);
    gemm_kernel<true><<<gblocks, tb, 0, stream>>>(aggbuf, ii, nullptr, W2, b2,
                                                  Wc, bc, d_out, n, gwaves);
}

// Round 18
// 218.955 us; speedup vs baseline: 1.3863x; 1.0513x over previous
//
#include <hip/hip_runtime.h>

// GCN: 2x GraphConv(norm='both') + leaky_relu + linear classifier.
// Interface (validated R6/R7): x/W/b f32, src/dst int32, out f32.
// R18 = R14/R17 + (a) oct-layout agg: wave = 8 nodes x 8 lanes x ushort8,
// one gather inst per 8 edges (was 4); (b) aggbuf in bf16 with ii folded at
// the agg write (bit-identical rounding, half the aggbuf traffic, gemm A =
// direct ushort8 loads). Laws (R8/R15/R16): gather kernels stay lean, no
// LDS, coalesced writes. ~57us/iter harness tax (d_ws poison fill + d_in
// restore) is not ours.

typedef __attribute__((ext_vector_type(8))) short short8;
typedef __attribute__((ext_vector_type(4))) float f32x4;

#define NPB 256      // partition blocks
#define BSH 9        // bucket shift (width 512)
#define BW  512      // bucket width; n <= 131072 -> <=256 buckets

__device__ __forceinline__ float b2f(unsigned short u) {
    return __uint_as_float(((unsigned int)u) << 16);
}
__device__ __forceinline__ unsigned short f2b(float f) {
    unsigned int i = __float_as_uint(f);
    unsigned int r = (i + 0x7FFFu + ((i >> 16) & 1u)) >> 16;  // RNE
    return (unsigned short)r;
}

// K1: per-partition-block LDS histograms by dst-bucket and src-bucket.
__global__ __launch_bounds__(256) void count_kernel(
    const int* __restrict__ src, const int* __restrict__ dst,
    int* __restrict__ cntD, int* __restrict__ cntS, int e, int chunk) {
    __shared__ int hD[256], hS[256];
    int t = threadIdx.x, pb = blockIdx.x;
    hD[t] = 0; hS[t] = 0;
    __syncthreads();
    int e0 = pb * chunk, e1 = min(e, e0 + chunk);
    for (int i = e0 + t; i < e1; i += 256) {
        atomicAdd(&hD[dst[i] >> BSH], 1);
        atomicAdd(&hS[src[i] >> BSH], 1);
    }
    __syncthreads();
    cntD[t * NPB + pb] = hD[t];
    cntS[t * NPB + pb] = hS[t];
}

// K2: exclusive scan of two 65536-int arrays (block 0: cntD, block 1: cntS)
__global__ __launch_bounds__(1024) void scanmat_kernel(int* __restrict__ cntD,
                                                       int* __restrict__ cntS) {
    int* a = (blockIdx.x == 0) ? cntD : cntS;
    __shared__ int s[1024];
    int t = threadIdx.x;
    int base = t * 64;
    int sum = 0;
    for (int j = 0; j < 64; j++) sum += a[base + j];
    s[t] = sum;
    __syncthreads();
    for (int d = 1; d < 1024; d <<= 1) {
        int x = (t >= d) ? s[t - d] : 0;
        __syncthreads();
        s[t] += x;
        __syncthreads();
    }
    int run = s[t] - sum;
    for (int j = 0; j < 64; j++) {
        int v = a[base + j];
        a[base + j] = run;
        run += v;
    }
}

// K3: partition. ebuf u32 = src<<9 | dstLocal; sbuf u16 = srcLocal.
__global__ __launch_bounds__(256) void part_kernel(
    const int* __restrict__ src, const int* __restrict__ dst,
    const int* __restrict__ cntD, const int* __restrict__ cntS,
    unsigned int* __restrict__ ebuf, unsigned short* __restrict__ sbuf,
    int e, int chunk) {
    __shared__ int cD[256], cS[256];
    int t = threadIdx.x, pb = blockIdx.x;
    cD[t] = cntD[t * NPB + pb];
    cS[t] = cntS[t * NPB + pb];
    __syncthreads();
    int e0 = pb * chunk, e1 = min(e, e0 + chunk);
    for (int i = e0 + t; i < e1; i += 256) {
        int s_ = src[i], d_ = dst[i];
        int pd = atomicAdd(&cD[d_ >> BSH], 1);
        ebuf[pd] = ((unsigned int)s_ << BSH) | (unsigned int)(d_ & (BW - 1));
        int ps_ = atomicAdd(&cS[s_ >> BSH], 1);
        sbuf[ps_] = (unsigned short)(s_ & (BW - 1));
    }
}

// K4: per-bucket fused: in-deg hist -> row/ii/cursors -> csr scatter;
// out-deg hist -> oi; x -> bf16*oi conversion for the bucket's nodes.
__global__ __launch_bounds__(256) void bucket_kernel(
    const unsigned int* __restrict__ ebuf, const unsigned short* __restrict__ sbuf,
    const int* __restrict__ cntD, const int* __restrict__ cntS,
    const float4* __restrict__ x4,
    int* __restrict__ row, float* __restrict__ ii, float* __restrict__ oi,
    int* __restrict__ csr, ushort4* __restrict__ xb, int n, int e) {
    __shared__ int cnt[BW], cur[BW], ocnt[BW], ps[256];
    __shared__ float ol[BW];
    int t = threadIdx.x, b = blockIdx.x;
    int v0 = b << BSH;
    int eb0 = cntD[b * NPB], eb1 = cntD[(b + 1) * NPB];
    int sb0 = cntS[b * NPB], sb1 = cntS[(b + 1) * NPB];
    cnt[t] = 0; cnt[t + 256] = 0;
    ocnt[t] = 0; ocnt[t + 256] = 0;
    __syncthreads();
    for (int i = eb0 + t; i < eb1; i += 256)
        atomicAdd(&cnt[ebuf[i] & (BW - 1)], 1);
    for (int i = sb0 + t; i < sb1; i += 256)
        atomicAdd(&ocnt[sbuf[i]], 1);
    __syncthreads();
    int c0 = cnt[2 * t], c1 = cnt[2 * t + 1];
    int pair = c0 + c1;
    ps[t] = pair;
    __syncthreads();
    for (int d = 1; d < 256; d <<= 1) {
        int x = (t >= d) ? ps[t - d] : 0;
        __syncthreads();
        ps[t] += x;
        __syncthreads();
    }
    int excl = ps[t] - pair;
    cur[2 * t] = excl;
    cur[2 * t + 1] = excl + c0;
    int v = v0 + 2 * t;
    if (v < n) {
        row[v] = eb0 + excl;
        ii[v] = rsqrtf((float)max(c0, 1));
    }
    if (v + 1 < n) {
        row[v + 1] = eb0 + excl + c0;
        ii[v + 1] = rsqrtf((float)max(c1, 1));
    }
    if (b == 0 && t == 0) row[n] = e;
    for (int j = t; j < BW; j += 256) {
        float o = rsqrtf((float)max(ocnt[j], 1));
        ol[j] = o;
        int vv = v0 + j;
        if (vv < n) oi[vv] = o;
    }
    __syncthreads();
    for (int i = eb0 + t; i < eb1; i += 256) {
        unsigned int p = ebuf[i];
        int r = atomicAdd(&cur[p & (BW - 1)], 1);
        csr[eb0 + r] = (int)(p >> BSH);
    }
    int nloc = min(BW, n - v0);
    for (int i = t; i < nloc * 16; i += 256) {
        int vl = i >> 4, q = i & 15;
        float s = ol[vl];
        float4 val = x4[(size_t)(v0 + vl) * 16 + q];
        xb[(size_t)(v0 + vl) * 16 + q] =
            make_ushort4(f2b(val.x * s), f2b(val.y * s), f2b(val.z * s), f2b(val.w * s));
    }
}

// Aggregate: wave = 8 nodes; oct o = lane>>3 owns node vbase+o; sublane
// s = lane&7 owns feats 8s..8s+7 (ushort8 = 16B). One gather inst serves
// 8 edges. Features pre-scaled by oi; output = bf16(sum * ii) (identical
// rounding to the previous gemm-side conversion).
__global__ __launch_bounds__(256) void agg_kernel(
    const short8* __restrict__ featb, const int* __restrict__ row,
    const int* __restrict__ csr, const float* __restrict__ ii,
    short8* __restrict__ outb, int n, int nwaves) {
    int lane = threadIdx.x & 63;
    int o = lane >> 3, s = lane & 7;
    int wid = blockIdx.x * (blockDim.x >> 6) + (threadIdx.x >> 6);
    int ngroups = (n + 7) >> 3;

    for (int g = wid; g < ngroups; g += nwaves) {
        int v = (g << 3) + o;
        bool valid = v < n;
        int base = 0, cnt = 0;
        if (valid) { base = row[v]; cnt = row[v + 1] - base; }
        float a[8];
#pragma unroll
        for (int k = 0; k < 8; k++) a[k] = 0.f;
        int j = 0;
        for (; j + 3 < cnt; j += 4) {
            int u[4];
#pragma unroll
            for (int k = 0; k < 4; k++) u[k] = csr[base + j + k];
#pragma unroll
            for (int k = 0; k < 4; k++) {
                short8 f = featb[(size_t)u[k] * 8 + s];
#pragma unroll
                for (int m = 0; m < 8; m++)
                    a[m] += b2f((unsigned short)f[m]);
            }
        }
        for (; j < cnt; j++) {
            short8 f = featb[(size_t)csr[base + j] * 8 + s];
#pragma unroll
            for (int m = 0; m < 8; m++)
                a[m] += b2f((unsigned short)f[m]);
        }
        if (valid) {
            float iiv = ii[v];
            short8 r;
#pragma unroll
            for (int m = 0; m < 8; m++) r[m] = (short)f2b(a[m] * iiv);
            outb[(size_t)v * 8 + s] = r;
        }
    }
}

// Transform: [n x 64] @ W[64 x 64] via mfma_f32_16x16x32_bf16 (layout
// verified R11). A read directly as bf16 (ii pre-folded by agg); bias+leaky
// epilogue. !FINAL: bf16 h1 pre-scaled by oi. FINAL: fused 64->2
// classifier, f32 out.
template <bool FINAL>
__global__ __launch_bounds__(256) void gemm_kernel(
    const unsigned short* __restrict__ aggb,
    const float* __restrict__ oi,
    const float* __restrict__ W, const float* __restrict__ bias,
    const float* __restrict__ Wc, const float* __restrict__ bcl,
    void* __restrict__ out, int n, int nwaves) {
    int lane = threadIdx.x & 63;
    int m15 = lane & 15, quad = lane >> 4;
    int wid = blockIdx.x * (blockDim.x >> 6) + (threadIdx.x >> 6);
    int ngroups = (n + 15) >> 4;

    short8 bf[4][2];
#pragma unroll
    for (int nt = 0; nt < 4; nt++)
#pragma unroll
        for (int kk = 0; kk < 2; kk++)
#pragma unroll
            for (int j = 0; j < 8; j++)
                bf[nt][kk][j] = (short)f2b(W[(kk * 32 + quad * 8 + j) * 64 + nt * 16 + m15]);

    float bias_r[4];
#pragma unroll
    for (int nt = 0; nt < 4; nt++) bias_r[nt] = bias[nt * 16 + m15];

    float wc_r[4][2];
    float bc0 = 0.f, bc1 = 0.f;
    if constexpr (FINAL) {
#pragma unroll
        for (int nt = 0; nt < 4; nt++) {
            wc_r[nt][0] = Wc[(nt * 16 + m15) * 2];
            wc_r[nt][1] = Wc[(nt * 16 + m15) * 2 + 1];
        }
        bc0 = bcl[0];
        bc1 = bcl[1];
    }

    for (int g = wid; g < ngroups; g += nwaves) {
        int rbase = g << 4;
        int rm = min(rbase + m15, n - 1);

        const short8* arow = (const short8*)(aggb + (size_t)rm * 64);
        short8 af0 = arow[quad];        // k = quad*8 .. quad*8+7
        short8 af1 = arow[4 + quad];    // k = 32 + quad*8 ..

        f32x4 acc[4];
#pragma unroll
        for (int nt = 0; nt < 4; nt++) {
            f32x4 z = {0.f, 0.f, 0.f, 0.f};
            z = __builtin_amdgcn_mfma_f32_16x16x32_bf16(af0, bf[nt][0], z, 0, 0, 0);
            z = __builtin_amdgcn_mfma_f32_16x16x32_bf16(af1, bf[nt][1], z, 0, 0, 0);
            acc[nt] = z;
        }

        if constexpr (!FINAL) {
#pragma unroll
            for (int r = 0; r < 4; r++) {
                int vr = rbase + quad * 4 + r;
                float os = (vr < n) ? oi[vr] : 0.f;
#pragma unroll
                for (int nt = 0; nt < 4; nt++) {
                    float o = acc[nt][r] + bias_r[nt];
                    o = (o > 0.f) ? o : 0.01f * o;
                    if (vr < n)
                        ((unsigned short*)out)[(size_t)vr * 64 + nt * 16 + m15] = f2b(o * os);
                }
            }
        } else {
#pragma unroll
            for (int r = 0; r < 4; r++) {
                float p0 = 0.f, p1 = 0.f;
#pragma unroll
                for (int nt = 0; nt < 4; nt++) {
                    float o = acc[nt][r] + bias_r[nt];
                    o = (o > 0.f) ? o : 0.01f * o;
                    p0 = fmaf(o, wc_r[nt][0], p0);
                    p1 = fmaf(o, wc_r[nt][1], p1);
                }
#pragma unroll
                for (int off = 1; off < 16; off <<= 1) {
                    p0 += __shfl_xor(p0, off);
                    p1 += __shfl_xor(p1, off);
                }
                int vr = rbase + quad * 4 + r;
                if (m15 == 0 && vr < n)
                    ((float2*)out)[vr] = make_float2(p0 + bc0, p1 + bc1);
            }
        }
    }
}

extern "C" void kernel_launch(void* const* d_in, const int* in_sizes, int n_in,
                              void* d_out, int out_size, void* d_ws, size_t ws_size,
                              hipStream_t stream) {
    const float* x  = (const float*)d_in[0];
    const int* src  = (const int*)d_in[1];
    const int* dst  = (const int*)d_in[2];
    const float* W1 = (const float*)d_in[3];
    const float* b1 = (const float*)d_in[4];
    const float* W2 = (const float*)d_in[5];
    const float* b2 = (const float*)d_in[6];
    const float* Wc = (const float*)d_in[7];
    const float* bc = (const float*)d_in[8];
    int n = in_sizes[0] / 64;
    int e = in_sizes[1];
    int total = n * 64;
    int nbuck = (n + BW - 1) >> BSH;

    char* ws = (char*)d_ws;
    size_t off = 0;
    auto take = [&](size_t bytes) -> char* {
        char* p = ws + off;
        off = (off + bytes + 255) & ~(size_t)255;
        return p;
    };
    int* cntD = (int*)take(256 * NPB * 4);
    int* cntS = (int*)take(256 * NPB * 4);
    unsigned int* ebuf = (unsigned int*)take((size_t)e * 4);     // 4 MB
    unsigned short* sbuf = (unsigned short*)take((size_t)e * 2); // 2 MB
    int* row  = (int*)take((size_t)(n + 1) * 4);
    int* csr  = (int*)take((size_t)e * 4);                       // 4 MB
    float* oi = (float*)take((size_t)n * 4);
    float* ii = (float*)take((size_t)n * 4);
    unsigned short* xb  = (unsigned short*)take((size_t)total * 2);  // 12.8 MB
    unsigned short* h1b = (unsigned short*)take((size_t)total * 2);  // 12.8 MB
    unsigned short* aggb = (unsigned short*)take((size_t)total * 2); // 12.8 MB

    const int tb = 256;
    int chunk = (e + NPB - 1) / NPB;

    count_kernel<<<NPB, tb, 0, stream>>>(src, dst, cntD, cntS, e, chunk);
    scanmat_kernel<<<2, 1024, 0, stream>>>(cntD, cntS);
    part_kernel<<<NPB, tb, 0, stream>>>(src, dst, cntD, cntS, ebuf, sbuf, e, chunk);
    bucket_kernel<<<nbuck, tb, 0, stream>>>(ebuf, sbuf, cntD, cntS, (const float4*)x,
                                            row, ii, oi, csr, (ushort4*)xb, n, e);

    const int ablocks = 2048;
    const int awaves = ablocks * (tb / 64);
    const int gblocks = 512;
    const int gwaves = gblocks * (tb / 64);

    // layer 1
    agg_kernel<<<ablocks, tb, 0, stream>>>((const short8*)xb, row, csr, ii,
                                           (short8*)aggb, n, awaves);
    gemm_kernel<false><<<gblocks, tb, 0, stream>>>(aggb, oi, W1, b1,
                                                   nullptr, nullptr, h1b, n, gwaves);
    // layer 2
    agg_kernel<<<ablocks, tb, 0, stream>>>((const short8*)h1b, row, csr, ii,
                                           (short8*)aggb, n, awaves);
    gemm_kernel<true><<<gblocks, tb, 0, stream>>>(aggb, oi, W2, b2,
                                                  Wc, bc, d_out, n, gwaves);
}